// Round 5
// baseline (291.309 us; speedup 1.0000x reference)
//
#include <hip/hip_runtime.h>
#include <math.h>

// Problem constants
#define B_   64
#define N_   197
#define C_   768
#define H_   12
#define HD_  64
#define BH_  (B_ * H_)          // 768
#define M_   (B_ * N_)          // 12608

typedef _Float16 half8 __attribute__((ext_vector_type(8)));
typedef float    f32x4 __attribute__((ext_vector_type(4)));

// Workspace byte offsets (16B aligned)
#define XH_OFF   0u           // 12608*768 fp16        = 19,365,888
#define WQH_OFF  19365888u    // 2304*768 fp16         =  3,538,944
#define WPH_OFF  22904832u    // 768*768 fp16          =  1,179,648
#define QH_OFF   24084480u    // [bh][197][64] fp16    = 19,365,888
#define KH_OFF   43450368u    // [bh][197][64] fp16    = 19,365,888
#define VT_OFF   62816256u    // [bh][64][224] fp16    = 22,020,096 (V transposed, key-padded)
#define OH_OFF   84836352u    // [B][N][C] fp16        = 19,365,888
#define P0_OFF   104202240u   // [bh][196] fp32        =    602,112
#define WS_BYTES 104804352u

__device__ __forceinline__ half8 h8zero() {
    half8 z;
    #pragma unroll
    for (int i = 0; i < 8; ++i) z[i] = (_Float16)0;
    return z;
}

// async global->LDS, 16 B per lane; LDS dest = wave-uniform base + lane*16
__device__ __forceinline__ void gld_lds16(const _Float16* g, _Float16* l) {
    __builtin_amdgcn_global_load_lds((const __attribute__((address_space(1))) void*)g,
                                     (__attribute__((address_space(3))) void*)l, 16, 0, 0);
}

// ---------------------------------------------------------------------------
__global__ void k_ws_too_small(float* out, float ws_bytes) { out[0] = -ws_bytes; }

// ---------------------------------------------------------------------------
// fp32 -> fp16 bulk convert
__global__ __launch_bounds__(256) void k_cvt(const float* __restrict__ src,
                                             _Float16* __restrict__ dst, int n8) {
    const int i = blockIdx.x * blockDim.x + threadIdx.x;
    if (i >= n8) return;
    float4 f0 = *(const float4*)(src + (size_t)i * 8);
    float4 f1 = *(const float4*)(src + (size_t)i * 8 + 4);
    half8 h;
    h[0]=(_Float16)f0.x; h[1]=(_Float16)f0.y; h[2]=(_Float16)f0.z; h[3]=(_Float16)f0.w;
    h[4]=(_Float16)f1.x; h[5]=(_Float16)f1.y; h[6]=(_Float16)f1.z; h[7]=(_Float16)f1.w;
    *(half8*)(dst + (size_t)i * 8) = h;
}

// zero Vt key-halves [192,224) per [bh][d] row; runs BEFORE k_qkv (which
// rewrites valid keys 192..196), leaving 197..223 zero.
__global__ __launch_bounds__(256) void k_vpad(_Float16* __restrict__ Vt) {
    const int i = blockIdx.x * 256 + threadIdx.x;   // 768*64*4 = 196608 exact
    const int row = i >> 2, c = i & 3;
    *(half8*)&Vt[(size_t)row * 224 + 192 + c * 8] = h8zero();
}

// ---------------------------------------------------------------------------
// NT-GEMM core (m97 pattern): 128x128 tile, BK=64 halves, global_load_lds
// width-16 staging into unpadded LDS (row stride 128 B) with XOR bank swizzle:
// LDS slot (row, s) holds A[row][16Bcol = s ^ (row&7)].
// A-frag: lane holds A[m=lane&15][k=(lane>>4)*8+j]; C/D: col=lane&15, row=quad*4+reg
__device__ __forceinline__ void mfma_nt_core(const _Float16* __restrict__ A,
                                             const _Float16* __restrict__ B,
                                             int K, int m0, int n0,
                                             _Float16* As, _Float16* Bs,
                                             f32x4 (&acc)[4][4]) {
    const int tid  = threadIdx.x;
    const int wave = tid >> 6, lane = tid & 63;
    const int wr   = (wave >> 1) << 6;
    const int wc   = (wave & 1) << 6;
    const int ln   = lane & 15, kq = lane >> 4;

    // staging: 4 issues per operand per iter; issue q covers rows q*32+(tid>>3),
    // 16B-slot s = tid&7, swizzled source col16 = s ^ (row&7)
    const int srow = tid >> 3;
    const int gc16 = (tid & 7) ^ (srow & 7);
    const _Float16* Ab = A + (size_t)(m0 + srow) * K + gc16 * 8;
    const _Float16* Bb = B + (size_t)(n0 + srow) * K + gc16 * 8;
    const size_t rstep = (size_t)32 * K;      // +32 rows per issue
    const int lbase = wave << 10;             // wave-uniform LDS byte base

    // fragment slot (halves): sl = ((ks*4+kq) ^ (ln&7)) * 8 = sl0 ^ (ks*32)
    const int sl0 = (kq ^ (ln & 7)) << 3;

    for (int k0 = 0; k0 < K; k0 += 64) {
        __syncthreads();                       // prior iter's frag reads done
        #pragma unroll
        for (int q = 0; q < 4; ++q) {
            gld_lds16(Ab + k0 + q * rstep, (_Float16*)((char*)As + (q << 12) + lbase));
            gld_lds16(Bb + k0 + q * rstep, (_Float16*)((char*)Bs + (q << 12) + lbase));
        }
        __syncthreads();                       // drains vmcnt (global_load_lds)
        #pragma unroll
        for (int ks = 0; ks < 2; ++ks) {
            const int so = sl0 ^ (ks << 5);
            half8 af[4], bf[4];
            #pragma unroll
            for (int t = 0; t < 4; ++t) {
                af[t] = *(const half8*)&As[((wr + t * 16 + ln) << 6) + so];
                bf[t] = *(const half8*)&Bs[((wc + t * 16 + ln) << 6) + so];
            }
            #pragma unroll
            for (int i = 0; i < 4; ++i)
                #pragma unroll
                for (int j = 0; j < 4; ++j)
                    acc[i][j] = __builtin_amdgcn_mfma_f32_16x16x32_f16(af[i], bf[j], acc[i][j], 0, 0, 0);
        }
    }
}

// ---------------------------------------------------------------------------
// qkv = x @ w_qkv^T; epilogue scatters Q(x0.125)/K -> [bh][n][64], V -> Vt[bh][d][224]
__global__ __launch_bounds__(256) void k_qkv_mfma(const _Float16* __restrict__ Xh,
                                                  const _Float16* __restrict__ Wq,
                                                  _Float16* __restrict__ Qh,
                                                  _Float16* __restrict__ Kh,
                                                  _Float16* __restrict__ Vt) {
    __shared__ _Float16 As[128 * 64];
    __shared__ _Float16 Bs[128 * 64];
    const int m0 = blockIdx.y << 7;
    const int n0 = blockIdx.x << 7;
    f32x4 acc[4][4] = {};
    mfma_nt_core(Xh, Wq, C_, m0, n0, As, Bs, acc);

    const int lane = threadIdx.x & 63;
    const int wave = threadIdx.x >> 6;
    const int wr = (wave >> 1) << 6, wc = (wave & 1) << 6;
    const int ln = lane & 15, kq = lane >> 4;
    #pragma unroll
    for (int mt = 0; mt < 4; ++mt) {
        #pragma unroll
        for (int i = 0; i < 4; ++i) {
            const int m = m0 + wr + mt * 16 + kq * 4 + i;
            if (m >= M_) continue;
            const int b = m / N_;
            const int n = m - b * N_;
            #pragma unroll
            for (int nt = 0; nt < 4; ++nt) {
                const int d  = n0 + wc + nt * 16 + ln;
                const int t3 = d / C_;
                const int rr = d - t3 * C_;
                const int h  = rr >> 6;
                const int e  = rr & 63;
                const int bh = b * H_ + h;
                const float v = acc[mt][nt][i];
                if      (t3 == 0) Qh[((size_t)bh * N_ + n) * HD_ + e] = (_Float16)(v * 0.125f);
                else if (t3 == 1) Kh[((size_t)bh * N_ + n) * HD_ + e] = (_Float16)v;
                else              Vt[((size_t)bh * HD_ + e) * 224 + n] = (_Float16)v;
            }
        }
    }
}

// ---------------------------------------------------------------------------
// out = O @ w_proj^T + b_proj
__global__ __launch_bounds__(256) void k_proj_mfma(const _Float16* __restrict__ Oh,
                                                   const _Float16* __restrict__ Wp,
                                                   const float* __restrict__ bias,
                                                   float* __restrict__ out) {
    __shared__ _Float16 As[128 * 64];
    __shared__ _Float16 Bs[128 * 64];
    const int m0 = blockIdx.y << 7;
    const int n0 = blockIdx.x << 7;
    f32x4 acc[4][4] = {};
    mfma_nt_core(Oh, Wp, C_, m0, n0, As, Bs, acc);

    const int lane = threadIdx.x & 63;
    const int wave = threadIdx.x >> 6;
    const int wr = (wave >> 1) << 6, wc = (wave & 1) << 6;
    const int ln = lane & 15, kq = lane >> 4;
    float bv[4];
    #pragma unroll
    for (int nt = 0; nt < 4; ++nt) bv[nt] = bias[n0 + wc + nt * 16 + ln];
    #pragma unroll
    for (int mt = 0; mt < 4; ++mt) {
        #pragma unroll
        for (int i = 0; i < 4; ++i) {
            const int m = m0 + wr + mt * 16 + kq * 4 + i;
            if (m >= M_) continue;
            #pragma unroll
            for (int nt = 0; nt < 4; ++nt)
                out[(size_t)m * C_ + n0 + wc + nt * 16 + ln] = acc[mt][nt][i] + bv[nt];
        }
    }
}

// ---------------------------------------------------------------------------
// Fused attention, per (64-row tile rt, bh). K and V fragments direct from
// global (L2-resident; V pre-transposed as Vt with zero pads). Only P does
// the LDS round-trip (C-layout -> A-layout). One barrier total.
__global__ __launch_bounds__(256) void k_attn(const _Float16* __restrict__ Qh,
                                              const _Float16* __restrict__ Kh,
                                              const _Float16* __restrict__ Vt,
                                              _Float16* __restrict__ Oh,
                                              float* __restrict__ P0) {
    __shared__ _Float16 Pl[4 * 16 * 232];    // per-wave 16x232 strip
    const int bh = blockIdx.y, rt = blockIdx.x;
    const int b = bh / H_, h = bh - b * H_;
    const int tid = threadIdx.x, wave = tid >> 6, lane = tid & 63;
    const int ln = lane & 15, kq = lane >> 4;
    const size_t kvb = (size_t)bh * N_ * HD_;
    const size_t vtb = (size_t)bh * HD_ * 224;

    // Q A-fragments direct from global
    const int qrow = rt * 64 + wave * 16 + ln;
    const _Float16* Qp = Qh + kvb + (size_t)((qrow < N_) ? qrow : 0) * HD_ + kq * 8;
    const half8 qf0 = *(const half8*)Qp;
    const half8 qf1 = *(const half8*)(Qp + 32);

    // S = Q K^T over 13 key tiles; K B-frags direct from global.
    // Keys 197..207 read neighboring data (finite) and are masked below.
    f32x4 acc[13] = {};
    #pragma unroll
    for (int c = 0; c < 13; ++c) {
        const _Float16* kp = Kh + kvb + (size_t)(c * 16 + ln) * HD_ + kq * 8;
        const half8 kf0 = *(const half8*)kp;
        const half8 kf1 = *(const half8*)(kp + 32);
        acc[c] = __builtin_amdgcn_mfma_f32_16x16x32_f16(qf0, kf0, acc[c], 0, 0, 0);
        acc[c] = __builtin_amdgcn_mfma_f32_16x16x32_f16(qf1, kf1, acc[c], 0, 0, 0);
    }
    // softmax per row (lane holds rows kq*4+r, cols c*16+ln); mask cols>=197
    float inv4[4];
    #pragma unroll
    for (int r = 0; r < 4; ++r) {
        float m = -1e30f;
        #pragma unroll
        for (int c = 0; c < 13; ++c) {
            float x = ((c * 16 + ln) < N_) ? acc[c][r] : -1e30f;
            acc[c][r] = x;
            m = fmaxf(m, x);
        }
        m = fmaxf(m, __shfl_xor(m, 1)); m = fmaxf(m, __shfl_xor(m, 2));
        m = fmaxf(m, __shfl_xor(m, 4)); m = fmaxf(m, __shfl_xor(m, 8));
        float s = 0.f;
        #pragma unroll
        for (int c = 0; c < 13; ++c) { float e = __expf(acc[c][r] - m); acc[c][r] = e; s += e; }
        s += __shfl_xor(s, 1); s += __shfl_xor(s, 2);
        s += __shfl_xor(s, 4); s += __shfl_xor(s, 8);
        inv4[r] = 1.f / s;
    }

    // P (fp16) -> own LDS strip; cols 197..207 are exp(-1e30)=0, 208..223 zeroed
    _Float16* Pw = Pl + wave * 16 * 232;
    #pragma unroll
    for (int c = 0; c < 13; ++c) {
        const int col = c * 16 + ln;
        #pragma unroll
        for (int r = 0; r < 4; ++r)
            Pw[(kq * 4 + r) * 232 + col] = (_Float16)(acc[c][r] * inv4[r]);
    }
    #pragma unroll
    for (int r = 0; r < 4; ++r) Pw[(kq * 4 + r) * 232 + 208 + ln] = (_Float16)0;

    // CLS-row probs for global_attn (row 0 = rt0/wave0/quad0/reg0)
    if (rt == 0 && wave == 0 && kq == 0) {
        #pragma unroll
        for (int c = 0; c < 13; ++c) {
            const int col = c * 16 + ln;
            if (col >= 1 && col < N_) P0[(size_t)bh * 196 + col - 1] = acc[c][0] * inv4[0];
        }
    }
    __syncthreads();   // safety: P strip visible before A-frag reads

    // O = P V: A-frags from LDS strip, B-frags direct from global Vt (pads zero)
    f32x4 o4[4] = {};
    #pragma unroll
    for (int t = 0; t < 7; ++t) {
        const half8 pf = *(const half8*)&Pw[ln * 232 + kq * 8 + 32 * t];
        #pragma unroll
        for (int n = 0; n < 4; ++n) {
            const half8 vf = *(const half8*)(Vt + vtb + (size_t)(n * 16 + ln) * 224 + kq * 8 + 32 * t);
            o4[n] = __builtin_amdgcn_mfma_f32_16x16x32_f16(pf, vf, o4[n], 0, 0, 0);
        }
    }
    // store O fp16 [B][N][C]
    const int g0 = rt * 64 + wave * 16 + kq * 4;
    #pragma unroll
    for (int r = 0; r < 4; ++r) {
        const int g = g0 + r;
        if (g >= N_) continue;
        _Float16* op = Oh + ((size_t)b * N_ + g) * C_ + h * HD_;
        #pragma unroll
        for (int n = 0; n < 4; ++n) op[n * 16 + ln] = (_Float16)o4[n][r];
    }
}

// ---------------------------------------------------------------------------
// global_attn[b][m] = mean_h P0[b*12+h][m]
__global__ void k_gattn(const float* __restrict__ P0, float* __restrict__ out2) {
    const int idx = blockIdx.x * blockDim.x + threadIdx.x;   // 12544 exact
    const int b = idx / (N_ - 1), m = idx - b * (N_ - 1);
    float s = 0.f;
    #pragma unroll
    for (int h = 0; h < H_; ++h) s += P0[((size_t)(b * H_ + h)) * 196 + m];
    out2[idx] = s * (1.f / H_);
}

// ---------------------------------------------------------------------------
extern "C" void kernel_launch(void* const* d_in, const int* in_sizes, int n_in,
                              void* d_out, int out_size, void* d_ws, size_t ws_size,
                              hipStream_t stream) {
    const float* x      = (const float*)d_in[0];
    const float* w_qkv  = (const float*)d_in[1];
    const float* w_proj = (const float*)d_in[2];
    const float* b_proj = (const float*)d_in[3];
    float* out = (float*)d_out;
    char* ws   = (char*)d_ws;

    if (ws_size < (size_t)WS_BYTES) {
        k_ws_too_small<<<1, 1, 0, stream>>>(out, (float)ws_size);
        return;
    }

    _Float16* Xh  = (_Float16*)(ws + XH_OFF);
    _Float16* Wqh = (_Float16*)(ws + WQH_OFF);
    _Float16* Wph = (_Float16*)(ws + WPH_OFF);
    _Float16* Qh  = (_Float16*)(ws + QH_OFF);
    _Float16* Kh  = (_Float16*)(ws + KH_OFF);
    _Float16* Vt  = (_Float16*)(ws + VT_OFF);
    _Float16* Oh  = (_Float16*)(ws + OH_OFF);
    float*    P0  = (float*)   (ws + P0_OFF);

    k_cvt<<<4728, 256, 0, stream>>>(x,      Xh,  1210368);
    k_cvt<<< 864, 256, 0, stream>>>(w_qkv,  Wqh, 221184);
    k_cvt<<< 288, 256, 0, stream>>>(w_proj, Wph, 73728);
    k_vpad<<<768, 256, 0, stream>>>(Vt);

    k_qkv_mfma <<<dim3(18, 99), 256, 0, stream>>>(Xh, Wqh, Qh, Kh, Vt);
    k_attn     <<<dim3(4, BH_), 256, 0, stream>>>(Qh, Kh, Vt, Oh, P0);
    k_gattn    <<<dim3(49),     256, 0, stream>>>(P0, out + (size_t)M_ * C_);
    k_proj_mfma<<<dim3(6, 99),  256, 0, stream>>>(Oh, Wph, b_proj, out);
}